// Round 1
// baseline (754.849 us; speedup 1.0000x reference)
//
#include <hip/hip_runtime.h>
#include <math.h>

#define N_STUDENT 100000
#define N_ITEM    20000
#define N_EDGES   1000000
#define IN_CH     128
#define EDGE_DIM  32
#define DEC_CH    64

// out[r][c] = act( sum_k X[r][k] * W[k][c] + (MODE==1 ? b[c] : 0) )
// MODE 0: identity (no bias), 1: softplus with bias
template<int MODE>
__global__ __launch_bounds__(256) void rowgemm_kernel(
    const float* __restrict__ X, const float* __restrict__ W,
    const float* __restrict__ b, float* __restrict__ out, int nrows)
{
    __shared__ float sW[IN_CH * DEC_CH];   // 32 KB
    {
        const float4* Wv = (const float4*)W;
        float4* sWv = (float4*)sW;
        for (int i = threadIdx.x; i < IN_CH * DEC_CH / 4; i += blockDim.x)
            sWv[i] = Wv[i];
    }
    __syncthreads();

    const int lane = threadIdx.x & 63;
    const int wib  = __builtin_amdgcn_readfirstlane(threadIdx.x >> 6);
    const int wave = blockIdx.x * (blockDim.x >> 6) + wib;
    const int nw   = gridDim.x * (blockDim.x >> 6);

    for (int r = wave; r < nrows; r += nw) {
        const float* xr = X + (size_t)r * IN_CH;   // wave-uniform -> s_load
        float acc = 0.f;
        #pragma unroll
        for (int k = 0; k < IN_CH; k += 8) {
            float xv[8];
            #pragma unroll
            for (int j = 0; j < 8; ++j) xv[j] = xr[k + j];
            #pragma unroll
            for (int j = 0; j < 8; ++j)
                acc = fmaf(xv[j], sW[(k + j) * DEC_CH + lane], acc);
        }
        if (MODE == 1) {
            acc += b[lane];
            // softplus = max(x,0) + log1p(exp(-|x|))
            acc = fmaxf(acc, 0.f) + log1pf(expf(-fabsf(acc)));
        }
        out[(size_t)r * DEC_CH + lane] = acc;
    }
}

__global__ __launch_bounds__(256) void edge_kernel(
    const int* __restrict__ idx, const float* __restrict__ ef,
    const float* __restrict__ W1, const float* __restrict__ b1,
    const float* __restrict__ offset, const float* __restrict__ s_part,
    const float* __restrict__ y_item, float* __restrict__ out)
{
    __shared__ float sWe[EDGE_DIM * DEC_CH];   // 8 KB (rows 128..159 of W1)
    __shared__ float sB[DEC_CH];
    {
        const float4* Wv = (const float4*)(W1 + IN_CH * DEC_CH);
        float4* sWv = (float4*)sWe;
        for (int i = threadIdx.x; i < EDGE_DIM * DEC_CH / 4; i += blockDim.x)
            sWv[i] = Wv[i];
        if (threadIdx.x < DEC_CH) sB[threadIdx.x] = b1[threadIdx.x];
    }
    __syncthreads();

    const int lane = threadIdx.x & 63;
    const int wib  = __builtin_amdgcn_readfirstlane(threadIdx.x >> 6);
    const int wave = blockIdx.x * (blockDim.x >> 6) + wib;
    const int nw   = gridDim.x * (blockDim.x >> 6);

    for (int e = wave; e < N_EDGES; e += nw) {
        const int is = idx[e];              // wave-uniform scalar loads
        const int ii = idx[N_EDGES + e];
        const float sv = s_part[(size_t)is * DEC_CH + lane];  // 256B coalesced gather
        const float yv = y_item[(size_t)ii * DEC_CH + lane];

        const float* efr = ef + (size_t)e * EDGE_DIM;  // wave-uniform -> s_load
        float acc = sB[lane];
        #pragma unroll
        for (int k = 0; k < EDGE_DIM; k += 8) {
            float ev[8];
            #pragma unroll
            for (int j = 0; j < 8; ++j) ev[j] = efr[k + j];
            #pragma unroll
            for (int j = 0; j < 8; ++j)
                acc = fmaf(ev[j], sWe[(k + j) * DEC_CH + lane], acc);
        }
        acc += sv;
        // ELU (alpha=1)
        const float x = acc > 0.f ? acc : expm1f(acc);
        float p = x * yv;
        #pragma unroll
        for (int off = 32; off >= 1; off >>= 1)
            p += __shfl_xor(p, off, 64);
        if (lane == 0) out[e] = p + offset[ii];
    }
}

extern "C" void kernel_launch(void* const* d_in, const int* in_sizes, int n_in,
                              void* d_out, int out_size, void* d_ws, size_t ws_size,
                              hipStream_t stream) {
    const float* x_student = (const float*)d_in[0];
    const float* x_item    = (const float*)d_in[1];
    const int*   eli       = (const int*)d_in[2];
    const float* edge_feat = (const float*)d_in[3];
    const float* offset    = (const float*)d_in[4];
    const float* W1        = (const float*)d_in[5];
    const float* b1        = (const float*)d_in[6];
    const float* W2        = (const float*)d_in[7];
    const float* b2        = (const float*)d_in[8];
    float* out = (float*)d_out;

    float* s_part = (float*)d_ws;                               // 100000*64 fp32 = 25.6 MB
    float* y_item = s_part + (size_t)N_STUDENT * DEC_CH;        // 20000*64 fp32 = 5.1 MB

    rowgemm_kernel<0><<<1024, 256, 0, stream>>>(x_student, W1, nullptr, s_part, N_STUDENT);
    rowgemm_kernel<1><<<512, 256, 0, stream>>>(x_item, W2, b2, y_item, N_ITEM);
    edge_kernel<<<2048, 256, 0, stream>>>(eli, edge_feat, W1, b1, offset, s_part, y_item, out);
}